// Round 8
// baseline (759.601 us; speedup 1.0000x reference)
//
#include <hip/hip_runtime.h>
#include <stdint.h>

#define NPOS 1024
#define NNEG 5
#define DD   128
#define NLEM 20000
#define BB   8
#define NTOK 1029   // NPOS + NNEG

// out-buffer section offsets (floats)
#define OFF_Y     163840000ULL
#define OFF_NOISE 163848192ULL
#define OFF_NM    163889152ULL

typedef short bf16x8 __attribute__((ext_vector_type(8)));
typedef float f32x4  __attribute__((ext_vector_type(4)));

#define LDS_STRIDE 136   // 128 + 8 pad shorts; 272 B rows

__device__ __forceinline__ uint16_t f2bf(float f) {
  union { float f; uint32_t u; } c; c.f = f;
  uint32_t u = c.u;
  return (uint16_t)((u + 0x7FFFu + ((u >> 16) & 1u)) >> 16);
}

// ---- convert x_pos (8x1024x128 rows of x) -> bf16 [8192][128] ----
__global__ void convert_x(const float* __restrict__ x, uint16_t* __restrict__ xb) {
  int t = blockIdx.x * 256 + threadIdx.x;   // 262144 threads, 4 elems each
  int e = t * 4;
  int row = e >> 7;
  int d   = e & 127;
  int b = row >> 10, p = row & 1023;
  float4 v = *(const float4*)(x + ((size_t)(b * NTOK + p)) * DD + d);
  ushort4 o;
  o.x = f2bf(v.x); o.y = f2bf(v.y); o.z = f2bf(v.z); o.w = f2bf(v.w);
  *(ushort4*)(xb + e) = o;
}

// ---- convert memory (20000x128) -> bf16 ----
__global__ void convert_mem(const float* __restrict__ m, uint16_t* __restrict__ mb) {
  size_t e = ((size_t)blockIdx.x * 256 + threadIdx.x) * 4;  // 640000 threads
  float4 v = *(const float4*)(m + e);
  ushort4 o;
  o.x = f2bf(v.x); o.y = f2bf(v.y); o.z = f2bf(v.z); o.w = f2bf(v.w);
  *(ushort4*)(mb + e) = o;
}

// ---- similarity: C[8192][20000] = Xb · Mb^T, bf16 MFMA, LDS-staged ----
// grid (125, 64); block 256 = 4 waves (2x2), block tile 128x160, wave tile 64x80
__global__ __launch_bounds__(256) void sim_mfma(const uint16_t* __restrict__ Xb,
                                                const uint16_t* __restrict__ Mb,
                                                float* __restrict__ out) {
  __shared__ uint16_t Xs[128 * LDS_STRIDE];   // 34816 B
  __shared__ uint16_t Ms[160 * LDS_STRIDE];   // 43520 B  (total 78336 B -> 2 blocks/CU)

  const int tid  = threadIdx.x;
  const int lane = tid & 63;
  const int wave = tid >> 6;
  const int wr = wave >> 1;                   // 0..1
  const int wc = wave & 1;                    // 0..1
  const int row0 = blockIdx.y * 128;
  const int col0 = blockIdx.x * 160;

  // ---- stage X tile: 128 rows x 128 bf16, 2048 16B-chunks, 8 iters ----
  #pragma unroll
  for (int it = 0; it < 8; it++) {
    int c = it * 256 + tid;
    int r = c >> 4, cc = c & 15;
    bf16x8 v = *(const bf16x8*)(Xb + (size_t)(row0 + r) * DD + cc * 8);
    *(bf16x8*)(Xs + r * LDS_STRIDE + cc * 8) = v;
  }
  // ---- stage M tile: 160 rows x 128 bf16, 2560 chunks, 10 iters ----
  #pragma unroll
  for (int it = 0; it < 10; it++) {
    int c = it * 256 + tid;
    int r = c >> 4, cc = c & 15;
    bf16x8 v = *(const bf16x8*)(Mb + (size_t)(col0 + r) * DD + cc * 8);
    *(bf16x8*)(Ms + r * LDS_STRIDE + cc * 8) = v;
  }
  __syncthreads();

  const int lrow = lane & 15;
  const int kk0  = (lane >> 4) * 8;
  f32x4 acc[4][5] = {};

  #pragma unroll
  for (int k0 = 0; k0 < DD; k0 += 32) {
    bf16x8 a[4], b[5];
    #pragma unroll
    for (int i = 0; i < 4; i++)
      a[i] = *(const bf16x8*)(Xs + (64 * wr + 16 * i + lrow) * LDS_STRIDE + k0 + kk0);
    #pragma unroll
    for (int j = 0; j < 5; j++)
      b[j] = *(const bf16x8*)(Ms + (80 * wc + 16 * j + lrow) * LDS_STRIDE + k0 + kk0);
    #pragma unroll
    for (int i = 0; i < 4; i++)
      #pragma unroll
      for (int j = 0; j < 5; j++)
        acc[i][j] = __builtin_amdgcn_mfma_f32_16x16x32_bf16(a[i], b[j], acc[i][j], 0, 0, 0);
  }

  const int rb = (lane >> 4) * 4;   // C/D: row=(lane>>4)*4+reg, col=lane&15 (m89-verified)
  const int cb = lane & 15;
  #pragma unroll
  for (int i = 0; i < 4; i++) {
    #pragma unroll
    for (int j = 0; j < 5; j++) {
      size_t base = (size_t)(row0 + 64 * wr + 16 * i + rb) * NLEM
                  + (size_t)(col0 + 80 * wc + 16 * j + cb);
      #pragma unroll
      for (int t = 0; t < 4; t++)
        __builtin_nontemporal_store(acc[i][j][t], &out[base + (size_t)t * NLEM]);
    }
  }
}

// ---- fp32 fallback if ws too small ----
__global__ void sim_f32(const float* __restrict__ x, const float* __restrict__ mem,
                        float* __restrict__ out) {
  size_t idx = (size_t)blockIdx.x * 256 + threadIdx.x;
  if (idx >= (size_t)BB * NPOS * NLEM) return;
  int col = (int)(idx % NLEM);
  int row = (int)(idx / NLEM);
  int b = row >> 10, p = row & 1023;
  const float* xr = x + ((size_t)(b * NTOK + p)) * DD;
  const float* mr = mem + (size_t)col * DD;
  float s = 0.f;
  #pragma unroll 8
  for (int d = 0; d < DD; d += 4) {
    float4 xv = *(const float4*)(xr + d);
    float4 mv = *(const float4*)(mr + d);
    s = fmaf(xv.x, mv.x, s); s = fmaf(xv.y, mv.y, s);
    s = fmaf(xv.z, mv.z, s); s = fmaf(xv.w, mv.w, s);
  }
  out[idx] = s;
}

// ---- noise similarity: (40 x 1024), fp32 ----
__global__ void noise_sim(const float* __restrict__ x, const float* __restrict__ mem,
                          float* __restrict__ on) {
  int t = blockIdx.x * 256 + threadIdx.x;   // 40960 exact
  int m = t & (NPOS - 1);
  int r = t >> 10;                          // 0..39 = b*5+n
  int b = r / NNEG, n = r - b * NNEG;
  const float* xr = x + ((size_t)(b * NTOK) + NPOS + n) * DD;
  const float* mr = mem + (size_t)m * DD;
  float s = 0.f;
  #pragma unroll 8
  for (int d = 0; d < DD; d += 4) {
    float4 xv = *(const float4*)(xr + d);
    float4 mv = *(const float4*)(mr + d);
    s = fmaf(xv.x, mv.x, s); s = fmaf(xv.y, mv.y, s);
    s = fmaf(xv.z, mv.z, s); s = fmaf(xv.w, mv.w, s);
  }
  on[t] = s;
}

// ---- y -> float ----
__global__ void ycopy(const int* __restrict__ y, float* __restrict__ oy) {
  int t = blockIdx.x * 256 + threadIdx.x;   // 8192 exact
  oy[t] = (float)y[t];
}

// ---- segment-sum scatter: acc[y[row]][d] += x_pos[row][d] * visible[row] ----
__global__ void scatter_seg(const float* __restrict__ x, const int* __restrict__ y,
                            const int* __restrict__ visible, float* acc) {
  int t = blockIdx.x * 256 + threadIdx.x;   // 1048576 exact
  int row = t >> 7;
  int d   = t & 127;
  if (visible[row]) {
    int b = row >> 10, p = row & 1023;
    float v = x[((size_t)(b * NTOK + p)) * DD + d];
    atomicAdd(&acc[(size_t)y[row] * DD + d], v);
  }
}

// ---- new_memory: build rows, L2-normalize; one wave per row ----
__global__ void newmem_kernel(const float* __restrict__ mem, const float* __restrict__ x,
                              const int* __restrict__ lru, float* nm) {
  int row  = blockIdx.x * 4 + (threadIdx.x >> 6);   // 20000 exact
  int lane = threadIdx.x & 63;
  int start = NPOS + lru[0] * NNEG * BB;
  int d = lane * 2;
  float2 v;
  if (row < NPOS) {
    float2 mv = *(const float2*)(mem + (size_t)row * DD + d);
    float2 av = *(const float2*)(nm + (size_t)row * DD + d);   // segment-sum accumulator
    v.x = 0.5f * mv.x + 0.0625f * av.x;   // 0.5*mem + (1-MOM)/B * sum
    v.y = 0.5f * mv.y + 0.0625f * av.y;
  } else if (row >= start && row < start + NNEG * BB) {
    int r = row - start;
    int b = r / NNEG, n = r - b * NNEG;
    v = *(const float2*)(x + ((size_t)(b * NTOK) + NPOS + n) * DD + d);
  } else {
    v = *(const float2*)(mem + (size_t)row * DD + d);
  }
  float ss = v.x * v.x + v.y * v.y;
  #pragma unroll
  for (int off = 1; off < 64; off <<= 1) ss += __shfl_xor(ss, off, 64);
  float inv = 1.0f / fmaxf(sqrtf(ss), 1e-12f);
  float2 o; o.x = v.x * inv; o.y = v.y * inv;
  *(float2*)(nm + (size_t)row * DD + d) = o;
}

extern "C" void kernel_launch(void* const* d_in, const int* in_sizes, int n_in,
                              void* d_out, int out_size, void* d_ws, size_t ws_size,
                              hipStream_t stream) {
  const float* x       = (const float*)d_in[0];
  const int*   y       = (const int*)d_in[1];
  const int*   visible = (const int*)d_in[2];
  const float* memory  = (const float*)d_in[3];
  const int*   lru     = (const int*)d_in[4];
  float* out = (float*)d_out;

  float* out_sim   = out;
  float* out_y     = out + OFF_Y;
  float* out_noise = out + OFF_NOISE;
  float* out_nm    = out + OFF_NM;

  // zero the segment-sum accumulator (first NPOS rows of new_memory section)
  hipMemsetAsync(out_nm, 0, (size_t)NPOS * DD * sizeof(float), stream);

  size_t need = (size_t)BB * NPOS * DD * 2 + (size_t)NLEM * DD * 2;  // bf16 copies
  if (ws_size >= need) {
    uint16_t* xb = (uint16_t*)d_ws;
    uint16_t* mb = xb + (size_t)BB * NPOS * DD;
    convert_x<<<1024, 256, 0, stream>>>(x, xb);
    convert_mem<<<2500, 256, 0, stream>>>(memory, mb);
    dim3 g(125, 64);
    sim_mfma<<<g, 256, 0, stream>>>(xb, mb, out_sim);
  } else {
    sim_f32<<<640000, 256, 0, stream>>>(x, memory, out_sim);
  }
  noise_sim<<<160, 256, 0, stream>>>(x, memory, out_noise);
  ycopy<<<32, 256, 0, stream>>>(y, out_y);
  scatter_seg<<<4096, 256, 0, stream>>>(x, y, visible, out_nm);
  newmem_kernel<<<5000, 256, 0, stream>>>(memory, x, lru, out_nm);
}

// Round 9
// 752.634 us; speedup vs baseline: 1.0093x; 1.0093x over previous
//
#include <hip/hip_runtime.h>
#include <stdint.h>

#define NPOS 1024
#define NNEG 5
#define DD   128
#define NLEM 20000
#define BB   8
#define NTOK 1029   // NPOS + NNEG

// out-buffer section offsets (floats)
#define OFF_Y     163840000ULL
#define OFF_NOISE 163848192ULL
#define OFF_NM    163889152ULL

typedef short bf16x8 __attribute__((ext_vector_type(8)));
typedef float f32x4  __attribute__((ext_vector_type(4)));

#define LDS_STRIDE 136   // operand rows: 128 + 8 pad shorts (272 B)
#define CS_STRIDE  164   // C-stage rows: 160 + 4 pad floats

__device__ __forceinline__ uint16_t f2bf(float f) {
  union { float f; uint32_t u; } c; c.f = f;
  uint32_t u = c.u;
  return (uint16_t)((u + 0x7FFFu + ((u >> 16) & 1u)) >> 16);
}

// ---- convert x_pos (8x1024x128 rows of x) -> bf16 [8192][128] ----
__global__ void convert_x(const float* __restrict__ x, uint16_t* __restrict__ xb) {
  int t = blockIdx.x * 256 + threadIdx.x;   // 262144 threads, 4 elems each
  int e = t * 4;
  int row = e >> 7;
  int d   = e & 127;
  int b = row >> 10, p = row & 1023;
  float4 v = *(const float4*)(x + ((size_t)(b * NTOK + p)) * DD + d);
  ushort4 o;
  o.x = f2bf(v.x); o.y = f2bf(v.y); o.z = f2bf(v.z); o.w = f2bf(v.w);
  *(ushort4*)(xb + e) = o;
}

// ---- convert memory (20000x128) -> bf16 ----
__global__ void convert_mem(const float* __restrict__ m, uint16_t* __restrict__ mb) {
  size_t e = ((size_t)blockIdx.x * 256 + threadIdx.x) * 4;  // 640000 threads
  float4 v = *(const float4*)(m + e);
  ushort4 o;
  o.x = f2bf(v.x); o.y = f2bf(v.y); o.z = f2bf(v.z); o.w = f2bf(v.w);
  *(ushort4*)(mb + e) = o;
}

// ---- similarity: C[8192][20000] = Xb · Mb^T, bf16 MFMA, LDS-staged,
//      contiguous-store epilogue through LDS C-staging ----
// grid (125, 128); block 256 = 4 waves (2x2), block tile 64x160, wave tile 32x80
__global__ __launch_bounds__(256) void sim_mfma(const uint16_t* __restrict__ Xb,
                                                const uint16_t* __restrict__ Mb,
                                                float* __restrict__ out) {
  __shared__ uint16_t smem[64 * LDS_STRIDE + 160 * LDS_STRIDE];  // 60928 B
  uint16_t* Xs = smem;                       // 64 rows
  uint16_t* Ms = smem + 64 * LDS_STRIDE;     // 160 rows
  float*    Cs = reinterpret_cast<float*>(smem);  // 64 x CS_STRIDE = 41984 B (aliased)

  const int tid  = threadIdx.x;
  const int lane = tid & 63;
  const int wave = tid >> 6;
  const int wr = wave >> 1;                   // 0..1
  const int wc = wave & 1;                    // 0..1
  const int row0 = blockIdx.y * 64;
  const int col0 = blockIdx.x * 160;

  // ---- stage X tile: 64 rows x 128 bf16 ----
  #pragma unroll
  for (int it = 0; it < 4; it++) {
    int c = it * 256 + tid;
    int r = c >> 4, cc = c & 15;
    bf16x8 v = *(const bf16x8*)(Xb + (size_t)(row0 + r) * DD + cc * 8);
    *(bf16x8*)(Xs + r * LDS_STRIDE + cc * 8) = v;
  }
  // ---- stage M tile: 160 rows x 128 bf16 ----
  #pragma unroll
  for (int it = 0; it < 10; it++) {
    int c = it * 256 + tid;
    int r = c >> 4, cc = c & 15;
    bf16x8 v = *(const bf16x8*)(Mb + (size_t)(col0 + r) * DD + cc * 8);
    *(bf16x8*)(Ms + r * LDS_STRIDE + cc * 8) = v;
  }
  __syncthreads();

  const int lrow = lane & 15;
  const int kk0  = (lane >> 4) * 8;
  f32x4 acc[2][5] = {};

  #pragma unroll
  for (int k0 = 0; k0 < DD; k0 += 32) {
    bf16x8 a[2], b[5];
    #pragma unroll
    for (int i = 0; i < 2; i++)
      a[i] = *(const bf16x8*)(Xs + (32 * wr + 16 * i + lrow) * LDS_STRIDE + k0 + kk0);
    #pragma unroll
    for (int j = 0; j < 5; j++)
      b[j] = *(const bf16x8*)(Ms + (80 * wc + 16 * j + lrow) * LDS_STRIDE + k0 + kk0);
    #pragma unroll
    for (int i = 0; i < 2; i++)
      #pragma unroll
      for (int j = 0; j < 5; j++)
        acc[i][j] = __builtin_amdgcn_mfma_f32_16x16x32_bf16(a[i], b[j], acc[i][j], 0, 0, 0);
  }

  // ---- epilogue: acc -> LDS (aliased over operand tiles) ----
  __syncthreads();   // all waves past their last ds_read of Xs/Ms
  const int rb = (lane >> 4) * 4;   // C/D: row=(lane>>4)*4+reg, col=lane&15 (m89-verified)
  const int cb = lane & 15;
  #pragma unroll
  for (int i = 0; i < 2; i++) {
    #pragma unroll
    for (int j = 0; j < 5; j++) {
      int crow = 32 * wr + 16 * i + rb;
      int ccol = 80 * wc + 16 * j + cb;
      #pragma unroll
      for (int t = 0; t < 4; t++)
        Cs[(crow + t) * CS_STRIDE + ccol] = acc[i][j][t];
    }
  }
  __syncthreads();

  // ---- contiguous stores: 2560 float4s, 10 iters, row-major ----
  #pragma unroll
  for (int it = 0; it < 10; it++) {
    int f  = it * 256 + tid;
    int r  = f / 40;          // 0..63
    int c4 = f - r * 40;      // 0..39
    f32x4 v = *(const f32x4*)(Cs + r * CS_STRIDE + c4 * 4);
    float* dst = out + (size_t)(row0 + r) * NLEM + (size_t)(col0 + c4 * 4);
    __builtin_nontemporal_store(v[0], dst + 0);
    __builtin_nontemporal_store(v[1], dst + 1);
    __builtin_nontemporal_store(v[2], dst + 2);
    __builtin_nontemporal_store(v[3], dst + 3);
  }
}

// ---- fp32 fallback if ws too small ----
__global__ void sim_f32(const float* __restrict__ x, const float* __restrict__ mem,
                        float* __restrict__ out) {
  size_t idx = (size_t)blockIdx.x * 256 + threadIdx.x;
  if (idx >= (size_t)BB * NPOS * NLEM) return;
  int col = (int)(idx % NLEM);
  int row = (int)(idx / NLEM);
  int b = row >> 10, p = row & 1023;
  const float* xr = x + ((size_t)(b * NTOK + p)) * DD;
  const float* mr = mem + (size_t)col * DD;
  float s = 0.f;
  #pragma unroll 8
  for (int d = 0; d < DD; d += 4) {
    float4 xv = *(const float4*)(xr + d);
    float4 mv = *(const float4*)(mr + d);
    s = fmaf(xv.x, mv.x, s); s = fmaf(xv.y, mv.y, s);
    s = fmaf(xv.z, mv.z, s); s = fmaf(xv.w, mv.w, s);
  }
  out[idx] = s;
}

// ---- noise similarity: (40 x 1024), fp32 ----
__global__ void noise_sim(const float* __restrict__ x, const float* __restrict__ mem,
                          float* __restrict__ on) {
  int t = blockIdx.x * 256 + threadIdx.x;   // 40960 exact
  int m = t & (NPOS - 1);
  int r = t >> 10;                          // 0..39 = b*5+n
  int b = r / NNEG, n = r - b * NNEG;
  const float* xr = x + ((size_t)(b * NTOK) + NPOS + n) * DD;
  const float* mr = mem + (size_t)m * DD;
  float s = 0.f;
  #pragma unroll 8
  for (int d = 0; d < DD; d += 4) {
    float4 xv = *(const float4*)(xr + d);
    float4 mv = *(const float4*)(mr + d);
    s = fmaf(xv.x, mv.x, s); s = fmaf(xv.y, mv.y, s);
    s = fmaf(xv.z, mv.z, s); s = fmaf(xv.w, mv.w, s);
  }
  on[t] = s;
}

// ---- y -> float ----
__global__ void ycopy(const int* __restrict__ y, float* __restrict__ oy) {
  int t = blockIdx.x * 256 + threadIdx.x;   // 8192 exact
  oy[t] = (float)y[t];
}

// ---- segment-sum scatter: acc[y[row]][d] += x_pos[row][d] * visible[row] ----
__global__ void scatter_seg(const float* __restrict__ x, const int* __restrict__ y,
                            const int* __restrict__ visible, float* acc) {
  int t = blockIdx.x * 256 + threadIdx.x;   // 1048576 exact
  int row = t >> 7;
  int d   = t & 127;
  if (visible[row]) {
    int b = row >> 10, p = row & 1023;
    float v = x[((size_t)(b * NTOK + p)) * DD + d];
    atomicAdd(&acc[(size_t)y[row] * DD + d], v);
  }
}

// ---- new_memory: build rows, L2-normalize; one wave per row ----
__global__ void newmem_kernel(const float* __restrict__ mem, const float* __restrict__ x,
                              const int* __restrict__ lru, float* nm) {
  int row  = blockIdx.x * 4 + (threadIdx.x >> 6);   // 20000 exact
  int lane = threadIdx.x & 63;
  int start = NPOS + lru[0] * NNEG * BB;
  int d = lane * 2;
  float2 v;
  if (row < NPOS) {
    float2 mv = *(const float2*)(mem + (size_t)row * DD + d);
    float2 av = *(const float2*)(nm + (size_t)row * DD + d);   // segment-sum accumulator
    v.x = 0.5f * mv.x + 0.0625f * av.x;   // 0.5*mem + (1-MOM)/B * sum
    v.y = 0.5f * mv.y + 0.0625f * av.y;
  } else if (row >= start && row < start + NNEG * BB) {
    int r = row - start;
    int b = r / NNEG, n = r - b * NNEG;
    v = *(const float2*)(x + ((size_t)(b * NTOK) + NPOS + n) * DD + d);
  } else {
    v = *(const float2*)(mem + (size_t)row * DD + d);
  }
  float ss = v.x * v.x + v.y * v.y;
  #pragma unroll
  for (int off = 1; off < 64; off <<= 1) ss += __shfl_xor(ss, off, 64);
  float inv = 1.0f / fmaxf(sqrtf(ss), 1e-12f);
  float2 o; o.x = v.x * inv; o.y = v.y * inv;
  *(float2*)(nm + (size_t)row * DD + d) = o;
}

extern "C" void kernel_launch(void* const* d_in, const int* in_sizes, int n_in,
                              void* d_out, int out_size, void* d_ws, size_t ws_size,
                              hipStream_t stream) {
  const float* x       = (const float*)d_in[0];
  const int*   y       = (const int*)d_in[1];
  const int*   visible = (const int*)d_in[2];
  const float* memory  = (const float*)d_in[3];
  const int*   lru     = (const int*)d_in[4];
  float* out = (float*)d_out;

  float* out_sim   = out;
  float* out_y     = out + OFF_Y;
  float* out_noise = out + OFF_NOISE;
  float* out_nm    = out + OFF_NM;

  // zero the segment-sum accumulator (first NPOS rows of new_memory section)
  hipMemsetAsync(out_nm, 0, (size_t)NPOS * DD * sizeof(float), stream);

  size_t need = (size_t)BB * NPOS * DD * 2 + (size_t)NLEM * DD * 2;  // bf16 copies
  if (ws_size >= need) {
    uint16_t* xb = (uint16_t*)d_ws;
    uint16_t* mb = xb + (size_t)BB * NPOS * DD;
    convert_x<<<1024, 256, 0, stream>>>(x, xb);
    convert_mem<<<2500, 256, 0, stream>>>(memory, mb);
    dim3 g(125, 128);
    sim_mfma<<<g, 256, 0, stream>>>(xb, mb, out_sim);
  } else {
    sim_f32<<<640000, 256, 0, stream>>>(x, memory, out_sim);
  }
  noise_sim<<<160, 256, 0, stream>>>(x, memory, out_noise);
  ycopy<<<32, 256, 0, stream>>>(y, out_y);
  scatter_seg<<<4096, 256, 0, stream>>>(x, y, visible, out_nm);
  newmem_kernel<<<5000, 256, 0, stream>>>(memory, x, lru, out_nm);
}